// Round 1
// baseline (799.502 us; speedup 1.0000x reference)
//
#include <hip/hip_runtime.h>
#include <hip/hip_bf16.h>

// GraphSAGE 2-layer, f32. Strategy:
//   build CSR (dst -> src adjacency) once per call, then two fused
//   atomic-free layer kernels: one wave (64 lanes) per node.
//   lane d accumulates feature d over in-edges (coalesced 256B gathers,
//   x/h are L3-resident), mean, then dense 64xD matmuls via per-wave LDS
//   broadcast of mean/self row against transposed weights (float4 streams).

#define WAVE 64

// ---- edge dtype detection: int64 buffers have all-zero odd int32 words ----
__global__ void detect_i64(const int* __restrict__ ei, int* __restrict__ flag) {
    int v = ei[2 * threadIdx.x + 1];
    if (v != 0) atomicOr(flag, 1);   // flag==1 -> int32 layout, flag==0 -> int64
}

__device__ __forceinline__ int edge_src(const int* ei, int E, int e, bool i64) {
    return i64 ? ei[2 * e] : ei[e];
}
__device__ __forceinline__ int edge_dst(const int* ei, int E, int e, bool i64) {
    return i64 ? ei[2 * E + 2 * e] : ei[E + e];
}

// ---- degree count ----
__global__ void k_deg(const int* __restrict__ ei, int E, const int* __restrict__ flag,
                      int* __restrict__ deg) {
    int t = blockIdx.x * blockDim.x + threadIdx.x;
    if (t >= E) return;
    bool i64 = (flag[0] == 0);
    atomicAdd(&deg[edge_dst(ei, E, t, i64)], 1);
}

// ---- 3-kernel exclusive scan over deg[0..n) -> rowstart, cursor ----
__global__ void scan_partials(const int* __restrict__ deg, int* __restrict__ partial, int n) {
    int b = blockIdx.x, t = threadIdx.x;
    int base = b * 1024 + t * 4;
    int s = 0;
#pragma unroll
    for (int i = 0; i < 4; ++i) { int idx = base + i; if (idx < n) s += deg[idx]; }
    __shared__ int lds[256];
    lds[t] = s; __syncthreads();
    for (int off = 128; off > 0; off >>= 1) {
        if (t < off) lds[t] += lds[t + off];
        __syncthreads();
    }
    if (t == 0) partial[b] = lds[0];
}

__global__ void scan_root(int* __restrict__ partial, int* __restrict__ rowstart,
                          int n, int total, int nb) {
    __shared__ int lds[1024];
    int t = threadIdx.x;
    int v = (t < nb) ? partial[t] : 0;
    lds[t] = v; __syncthreads();
    for (int off = 1; off < 1024; off <<= 1) {
        int add = (t >= off) ? lds[t - off] : 0;
        __syncthreads();
        lds[t] += add;
        __syncthreads();
    }
    if (t < nb) partial[t] = lds[t] - v;   // exclusive block offsets (in-place)
    if (t == 0) rowstart[n] = total;
}

__global__ void scan_final(const int* __restrict__ deg, const int* __restrict__ partial,
                           int* __restrict__ rowstart, int* __restrict__ cursor, int n) {
    int b = blockIdx.x, t = threadIdx.x;
    int base = b * 1024 + t * 4;
    int v[4]; int s = 0;
#pragma unroll
    for (int i = 0; i < 4; ++i) { int idx = base + i; v[i] = (idx < n) ? deg[idx] : 0; s += v[i]; }
    __shared__ int lds[256];
    lds[t] = s; __syncthreads();
    for (int off = 1; off < 256; off <<= 1) {
        int add = (t >= off) ? lds[t - off] : 0;
        __syncthreads();
        lds[t] += add;
        __syncthreads();
    }
    int excl = lds[t] - s + partial[b];
#pragma unroll
    for (int i = 0; i < 4; ++i) {
        int idx = base + i;
        if (idx < n) { rowstart[idx] = excl; cursor[idx] = excl; }
        excl += v[i];
    }
}

// ---- fill adjacency (order within a row is nondeterministic; fp-sum tolerance ok) ----
__global__ void k_fill(const int* __restrict__ ei, int E, const int* __restrict__ flag,
                       int* __restrict__ cursor, int* __restrict__ adj) {
    int t = blockIdx.x * blockDim.x + threadIdx.x;
    if (t >= E) return;
    bool i64 = (flag[0] == 0);
    int s = edge_src(ei, E, t, i64);
    int d = edge_dst(ei, E, t, i64);
    int pos = atomicAdd(&cursor[d], 1);
    adj[pos] = s;
}

// ---- transpose all four weight matrices into ws:  Wt[j][k] = W[k][j] ----
// layout in wT: [0,4096) Wlt1 | [4096,8192) Wrt1 | [8192,10240) Wlt2 | [10240,12288) Wrt2
__global__ void k_prep(const float* __restrict__ Wl1, const float* __restrict__ Wr1,
                       const float* __restrict__ Wl2, const float* __restrict__ Wr2,
                       float* __restrict__ wT) {
    int idx = blockIdx.x * blockDim.x + threadIdx.x;
    if (idx >= 12288) return;
    if (idx < 4096) {
        int j = idx >> 6, k = idx & 63;
        wT[idx] = Wl1[k * 64 + j];
    } else if (idx < 8192) {
        int r = idx - 4096; int j = r >> 6, k = r & 63;
        wT[idx] = Wr1[k * 64 + j];
    } else if (idx < 10240) {
        int r = idx - 8192; int j = r >> 6, k = r & 63;
        wT[idx] = Wl2[k * 32 + j];
    } else {
        int r = idx - 10240; int j = r >> 6, k = r & 63;
        wT[idx] = Wr2[k * 32 + j];
    }
}

// ---- fused SAGE layer: one wave per node ----
// out[v] = bias + mean_neighbors(xin) @ Wl + xin[v] @ Wr   (optional relu)
// Wlt/Wrt are transposed: lane j streams row j (64 contiguous floats).
template <int DOUT, bool RELU>
__global__ __launch_bounds__(256) void sage_layer(
        const float* __restrict__ xin, const int* __restrict__ rowstart,
        const int* __restrict__ adj, const float* __restrict__ Wlt,
        const float* __restrict__ Wrt, const float* __restrict__ bias,
        float* __restrict__ out, int n) {
    __shared__ float sm[4][64];
    __shared__ float sx[4][64];
    int w = threadIdx.x >> 6, lane = threadIdx.x & 63;
    int v = blockIdx.x * 4 + w;
    if (v >= n) return;

    int s0 = rowstart[v], s1 = rowstart[v + 1];
    float acc = 0.f;
    int e = s0;
    for (; e + 4 <= s1; e += 4) {
        int n0 = adj[e], n1 = adj[e + 1], n2 = adj[e + 2], n3 = adj[e + 3];
        float a0 = xin[n0 * 64 + lane];
        float a1 = xin[n1 * 64 + lane];
        float a2 = xin[n2 * 64 + lane];
        float a3 = xin[n3 * 64 + lane];
        acc += a0 + a1 + a2 + a3;
    }
    for (; e < s1; ++e) acc += xin[adj[e] * 64 + lane];

    float mean = acc / fmaxf((float)(s1 - s0), 1.f);
    float xv = xin[v * 64 + lane];
    // wave-local LDS staging (lockstep wave64; compiler orders ds_write->ds_read)
    sm[w][lane] = mean;
    sx[w][lane] = xv;

    if (lane < DOUT) {
        const float4* wlr = (const float4*)(Wlt + lane * 64);
        const float4* wrr = (const float4*)(Wrt + lane * 64);
        const float4* m4 = (const float4*)sm[w];
        const float4* x4 = (const float4*)sx[w];
        float o = bias[lane];
#pragma unroll
        for (int k = 0; k < 16; ++k) {
            float4 a = wlr[k], b = wrr[k], mm = m4[k], xx = x4[k];
            o += mm.x * a.x + mm.y * a.y + mm.z * a.z + mm.w * a.w;
            o += xx.x * b.x + xx.y * b.y + xx.z * b.z + xx.w * b.w;
        }
        if (RELU) o = fmaxf(o, 0.f);
        out[v * DOUT + lane] = o;
    }
}

extern "C" void kernel_launch(void* const* d_in, const int* in_sizes, int n_in,
                              void* d_out, int out_size, void* d_ws, size_t ws_size,
                              hipStream_t stream) {
    const float* x   = (const float*)d_in[0];
    const int*   ei  = (const int*)d_in[1];
    const float* Wl1 = (const float*)d_in[2];
    const float* Wr1 = (const float*)d_in[3];
    const float* b1  = (const float*)d_in[4];
    const float* Wl2 = (const float*)d_in[5];
    const float* Wr2 = (const float*)d_in[6];
    const float* b2  = (const float*)d_in[7];

    int N = in_sizes[0] / 64;
    int E = in_sizes[1] / 2;

    char* ws = (char*)d_ws;
    size_t o = 0;
    auto alloc = [&](size_t bytes) -> char* {
        char* p = ws + o;
        o = (o + bytes + 255) & ~(size_t)255;
        return p;
    };
    int* deg      = (int*)alloc((size_t)N * 4 + 4);   // deg[N] + flag
    int* flag     = deg + N;
    int* rowstart = (int*)alloc((size_t)(N + 1) * 4);
    int* cursor   = (int*)alloc((size_t)N * 4);
    int* partial  = (int*)alloc(4096);
    int* adj      = (int*)alloc((size_t)E * 4);
    float* wT     = (float*)alloc(12288 * 4);
    float* h      = (float*)alloc((size_t)N * 64 * 4);

    hipMemsetAsync(deg, 0, (size_t)N * 4 + 4, stream);

    detect_i64<<<1, 256, 0, stream>>>(ei, flag);
    k_prep<<<48, 256, 0, stream>>>(Wl1, Wr1, Wl2, Wr2, wT);

    int eb = (E + 255) / 256;
    k_deg<<<eb, 256, 0, stream>>>(ei, E, flag, deg);

    int NB = (N + 1023) / 1024;
    scan_partials<<<NB, 256, 0, stream>>>(deg, partial, N);
    scan_root<<<1, 1024, 0, stream>>>(partial, rowstart, N, E, NB);
    scan_final<<<NB, 256, 0, stream>>>(deg, partial, rowstart, cursor, N);

    k_fill<<<eb, 256, 0, stream>>>(ei, E, flag, cursor, adj);

    int nb4 = (N + 3) / 4;
    sage_layer<64, true ><<<nb4, 256, 0, stream>>>(x, rowstart, adj, wT, wT + 4096, b1, h, N);
    sage_layer<32, false><<<nb4, 256, 0, stream>>>(h, rowstart, adj, wT + 8192, wT + 10240, b2,
                                                   (float*)d_out, N);
}

// Round 2
// 793.822 us; speedup vs baseline: 1.0072x; 1.0072x over previous
//
#include <hip/hip_runtime.h>
#include <hip/hip_bf16.h>

// GraphSAGE 2-layer, f32. CSR build (dst->src), then:
//   agg1: per-node wave, 16-deep batched gathers of x rows (256B each),
//         mean, fused epilogue mean@Wl1 + x@Wr1 + b1, relu -> h,
//         plus fused z2 = h@Wl2 (pre-transform for layer 2).
//   agg2: per-node wave, half-wave (2 edges/iter) batched gathers of z2
//         rows (128B), mean, + h@Wr2 + b2 -> out.
// Gathers are latency-bound: batches of 16 independent loads per wave.

// ---- edge dtype detection: int64 buffers have all-zero odd int32 words ----
__global__ void detect_i64(const int* __restrict__ ei, int* __restrict__ flag) {
    int v = ei[2 * threadIdx.x + 1];
    if (v != 0) atomicOr(flag, 1);   // 1 -> int32 layout, 0 -> int64
}

__device__ __forceinline__ int edge_src(const int* ei, int E, int e, bool i64) {
    return i64 ? ei[2 * e] : ei[e];
}
__device__ __forceinline__ int edge_dst(const int* ei, int E, int e, bool i64) {
    return i64 ? ei[2 * E + 2 * e] : ei[E + e];
}

// ---- degree count ----
__global__ void k_deg(const int* __restrict__ ei, int E, const int* __restrict__ flag,
                      int* __restrict__ deg) {
    int t = blockIdx.x * blockDim.x + threadIdx.x;
    if (t >= E) return;
    bool i64 = (flag[0] == 0);
    atomicAdd(&deg[edge_dst(ei, E, t, i64)], 1);
}

// ---- 3-kernel exclusive scan over deg[0..n) -> rowstart, cursor ----
__global__ void scan_partials(const int* __restrict__ deg, int* __restrict__ partial, int n) {
    int b = blockIdx.x, t = threadIdx.x;
    int base = b * 1024 + t * 4;
    int s = 0;
#pragma unroll
    for (int i = 0; i < 4; ++i) { int idx = base + i; if (idx < n) s += deg[idx]; }
    __shared__ int lds[256];
    lds[t] = s; __syncthreads();
    for (int off = 128; off > 0; off >>= 1) {
        if (t < off) lds[t] += lds[t + off];
        __syncthreads();
    }
    if (t == 0) partial[b] = lds[0];
}

__global__ void scan_root(int* __restrict__ partial, int* __restrict__ rowstart,
                          int n, int total, int nb) {
    __shared__ int lds[1024];
    int t = threadIdx.x;
    int v = (t < nb) ? partial[t] : 0;
    lds[t] = v; __syncthreads();
    for (int off = 1; off < 1024; off <<= 1) {
        int add = (t >= off) ? lds[t - off] : 0;
        __syncthreads();
        lds[t] += add;
        __syncthreads();
    }
    if (t < nb) partial[t] = lds[t] - v;   // exclusive block offsets
    if (t == 0) rowstart[n] = total;
}

__global__ void scan_final(const int* __restrict__ deg, const int* __restrict__ partial,
                           int* __restrict__ rowstart, int* __restrict__ cursor, int n) {
    int b = blockIdx.x, t = threadIdx.x;
    int base = b * 1024 + t * 4;
    int v[4]; int s = 0;
#pragma unroll
    for (int i = 0; i < 4; ++i) { int idx = base + i; v[i] = (idx < n) ? deg[idx] : 0; s += v[i]; }
    __shared__ int lds[256];
    lds[t] = s; __syncthreads();
    for (int off = 1; off < 256; off <<= 1) {
        int add = (t >= off) ? lds[t - off] : 0;
        __syncthreads();
        lds[t] += add;
        __syncthreads();
    }
    int excl = lds[t] - s + partial[b];
#pragma unroll
    for (int i = 0; i < 4; ++i) {
        int idx = base + i;
        if (idx < n) { rowstart[idx] = excl; cursor[idx] = excl; }
        excl += v[i];
    }
}

// ---- fill adjacency ----
__global__ void k_fill(const int* __restrict__ ei, int E, const int* __restrict__ flag,
                       int* __restrict__ cursor, int* __restrict__ adj) {
    int t = blockIdx.x * blockDim.x + threadIdx.x;
    if (t >= E) return;
    bool i64 = (flag[0] == 0);
    int s = edge_src(ei, E, t, i64);
    int d = edge_dst(ei, E, t, i64);
    int pos = atomicAdd(&cursor[d], 1);
    adj[pos] = s;
}

// ---- transpose weights: wT layout:
// [0,4096) Wl1t | [4096,8192) Wr1t | [8192,10240) Wl2t | [10240,12288) Wr2t
__global__ void k_prep(const float* __restrict__ Wl1, const float* __restrict__ Wr1,
                       const float* __restrict__ Wl2, const float* __restrict__ Wr2,
                       float* __restrict__ wT) {
    int idx = blockIdx.x * blockDim.x + threadIdx.x;
    if (idx >= 12288) return;
    if (idx < 4096) {
        int j = idx >> 6, k = idx & 63;
        wT[idx] = Wl1[k * 64 + j];
    } else if (idx < 8192) {
        int r = idx - 4096; int j = r >> 6, k = r & 63;
        wT[idx] = Wr1[k * 64 + j];
    } else if (idx < 10240) {
        int r = idx - 8192; int j = r >> 6, k = r & 63;
        wT[idx] = Wl2[k * 32 + j];
    } else {
        int r = idx - 10240; int j = r >> 6, k = r & 63;
        wT[idx] = Wr2[k * 32 + j];
    }
}

__device__ __forceinline__ float dot64(const float* __restrict__ a,
                                       const float* __restrict__ b) {
    const float4* a4 = (const float4*)a;
    const float4* b4 = (const float4*)b;
    float s = 0.f;
#pragma unroll
    for (int k = 0; k < 16; ++k) {
        float4 p = a4[k], q = b4[k];
        s += p.x * q.x + p.y * q.y + p.z * q.z + p.w * q.w;
    }
    return s;
}

// ---- layer 1 fused: gather x, mean, mean@Wl1 + x@Wr1 + b1, relu -> h; z2 = h@Wl2 ----
__global__ __launch_bounds__(256) void agg1(
        const float* __restrict__ x, const int* __restrict__ rowstart,
        const int* __restrict__ adj, const float* __restrict__ wT,
        const float* __restrict__ b1, float* __restrict__ h,
        float* __restrict__ z2, int n) {
    __shared__ float sm[4][64];
    __shared__ float sx[4][64];
    __shared__ float sh[4][64];
    int w = threadIdx.x >> 6, lane = threadIdx.x & 63;
    int v = blockIdx.x * 4 + w;
    if (v >= n) return;

    int s0 = rowstart[v], s1 = rowstart[v + 1];
    float xv = x[v * 64 + lane];          // self row, issued early
    float acc = 0.f;
    int last = s1 - 1;
    for (int e = s0; e < s1; e += 16) {
        float a[16];
#pragma unroll
        for (int t = 0; t < 16; ++t) {
            int idx = e + t; idx = idx > last ? last : idx;
            a[t] = x[adj[idx] * 64 + lane];      // 16 independent gathers in flight
        }
#pragma unroll
        for (int t = 0; t < 16; ++t) acc += (e + t <= last) ? a[t] : 0.f;
    }
    float mean = acc / fmaxf((float)(s1 - s0), 1.f);

    sm[w][lane] = mean;
    sx[w][lane] = xv;
    __builtin_amdgcn_wave_barrier();
    float o = b1[lane] + dot64(sm[w], wT + lane * 64)           // mean @ Wl1
                       + dot64(sx[w], wT + 4096 + lane * 64);   // x @ Wr1
    o = fmaxf(o, 0.f);
    h[v * 64 + lane] = o;

    sh[w][lane] = o;
    __builtin_amdgcn_wave_barrier();
    if (lane < 32)
        z2[v * 32 + lane] = dot64(sh[w], wT + 8192 + lane * 64); // h @ Wl2
}

// ---- layer 2 fused: gather z2 (32-dim, 2 edges/half-wave), mean, + h@Wr2 + b2 ----
__global__ __launch_bounds__(256) void agg2(
        const float* __restrict__ z2, const float* __restrict__ h,
        const int* __restrict__ rowstart, const int* __restrict__ adj,
        const float* __restrict__ wT, const float* __restrict__ b2,
        float* __restrict__ out, int n) {
    __shared__ float sh[4][64];
    int w = threadIdx.x >> 6, lane = threadIdx.x & 63;
    int v = blockIdx.x * 4 + w;
    if (v >= n) return;

    int s0 = rowstart[v], s1 = rowstart[v + 1];
    float hv = h[v * 64 + lane];          // self row, issued early
    int f = lane & 31, hh = lane >> 5;
    float acc = 0.f;
    int last = s1 - 1;
    for (int e = s0; e < s1; e += 32) {   // 32 edges per iter: 16 per half-wave
        float a[16];
#pragma unroll
        for (int t = 0; t < 16; ++t) {
            int idx = e + 2 * t + hh; idx = idx > last ? last : idx;
            a[t] = z2[adj[idx] * 32 + f];
        }
#pragma unroll
        for (int t = 0; t < 16; ++t) acc += (e + 2 * t + hh <= last) ? a[t] : 0.f;
    }
    acc += __shfl_xor(acc, 32);           // combine half-waves
    float mean = acc / fmaxf((float)(s1 - s0), 1.f);

    sh[w][lane] = hv;
    __builtin_amdgcn_wave_barrier();
    if (lane < 32)
        out[v * 32 + lane] = mean + b2[lane]
                           + dot64(sh[w], wT + 10240 + lane * 64);  // h @ Wr2
}

extern "C" void kernel_launch(void* const* d_in, const int* in_sizes, int n_in,
                              void* d_out, int out_size, void* d_ws, size_t ws_size,
                              hipStream_t stream) {
    const float* x   = (const float*)d_in[0];
    const int*   ei  = (const int*)d_in[1];
    const float* Wl1 = (const float*)d_in[2];
    const float* Wr1 = (const float*)d_in[3];
    const float* b1  = (const float*)d_in[4];
    const float* Wl2 = (const float*)d_in[5];
    const float* Wr2 = (const float*)d_in[6];
    const float* b2  = (const float*)d_in[7];

    int N = in_sizes[0] / 64;
    int E = in_sizes[1] / 2;

    char* ws = (char*)d_ws;
    size_t o = 0;
    auto alloc = [&](size_t bytes) -> char* {
        char* p = ws + o;
        o = (o + bytes + 255) & ~(size_t)255;
        return p;
    };
    int* deg      = (int*)alloc((size_t)N * 4 + 4);   // deg[N] + flag
    int* flag     = deg + N;
    int* rowstart = (int*)alloc((size_t)(N + 1) * 4);
    int* cursor   = (int*)alloc((size_t)N * 4);
    int* partial  = (int*)alloc(4096);
    int* adj      = (int*)alloc((size_t)E * 4);
    float* wT     = (float*)alloc(12288 * 4);
    float* h      = (float*)alloc((size_t)N * 64 * 4);
    float* z2     = (float*)alloc((size_t)N * 32 * 4);

    hipMemsetAsync(deg, 0, (size_t)N * 4 + 4, stream);

    detect_i64<<<1, 256, 0, stream>>>(ei, flag);
    k_prep<<<48, 256, 0, stream>>>(Wl1, Wr1, Wl2, Wr2, wT);

    int eb = (E + 255) / 256;
    k_deg<<<eb, 256, 0, stream>>>(ei, E, flag, deg);

    int NB = (N + 1023) / 1024;
    scan_partials<<<NB, 256, 0, stream>>>(deg, partial, N);
    scan_root<<<1, 1024, 0, stream>>>(partial, rowstart, N, E, NB);
    scan_final<<<NB, 256, 0, stream>>>(deg, partial, rowstart, cursor, N);

    k_fill<<<eb, 256, 0, stream>>>(ei, E, flag, cursor, adj);

    int nb4 = (N + 3) / 4;
    agg1<<<nb4, 256, 0, stream>>>(x, rowstart, adj, wT, b1, h, z2, N);
    agg2<<<nb4, 256, 0, stream>>>(z2, h, rowstart, adj, wT, b2, (float*)d_out, N);
}

// Round 3
// 308.897 us; speedup vs baseline: 2.5882x; 2.5699x over previous
//
#include <hip/hip_runtime.h>
#include <hip/hip_bf16.h>

// GraphSAGE 2-layer f32. mean-aggregation is linear, so transform-then-
// aggregate: P1 = x@Wl1, S1 = x@Wr1+b1 (dense, block GEMV w/ scalar weights),
// h = relu(mean_agg(P1) + S1) (pure gather), z2|S2 = h@[Wl2|Wr2+b2],
// out = mean_agg(z2) + S2 (pure gather). CSR built per call.

// ---- edge dtype detection: int64 buffers have all-zero odd int32 words ----
__global__ void detect_i64(const int* __restrict__ ei, int* __restrict__ flag) {
    int v = ei[2 * threadIdx.x + 1];
    if (v != 0) atomicOr(flag, 1);   // 1 -> int32 layout, 0 -> int64
}

__device__ __forceinline__ int edge_src(const int* ei, int E, int e, bool i64) {
    return i64 ? ei[2 * e] : ei[e];
}
__device__ __forceinline__ int edge_dst(const int* ei, int E, int e, bool i64) {
    return i64 ? ei[2 * E + 2 * e] : ei[E + e];
}

__global__ void k_deg(const int* __restrict__ ei, int E, const int* __restrict__ flag,
                      int* __restrict__ deg) {
    int t = blockIdx.x * blockDim.x + threadIdx.x;
    if (t >= E) return;
    bool i64 = (flag[0] == 0);
    atomicAdd(&deg[edge_dst(ei, E, t, i64)], 1);
}

// ---- 3-kernel exclusive scan over deg[0..n) -> rowstart, cursor ----
__global__ void scan_partials(const int* __restrict__ deg, int* __restrict__ partial, int n) {
    int b = blockIdx.x, t = threadIdx.x;
    int base = b * 1024 + t * 4;
    int s = 0;
#pragma unroll
    for (int i = 0; i < 4; ++i) { int idx = base + i; if (idx < n) s += deg[idx]; }
    __shared__ int lds[256];
    lds[t] = s; __syncthreads();
    for (int off = 128; off > 0; off >>= 1) {
        if (t < off) lds[t] += lds[t + off];
        __syncthreads();
    }
    if (t == 0) partial[b] = lds[0];
}

__global__ void scan_root(int* __restrict__ partial, int* __restrict__ rowstart,
                          int n, int total, int nb) {
    __shared__ int lds[1024];
    int t = threadIdx.x;
    int v = (t < nb) ? partial[t] : 0;
    lds[t] = v; __syncthreads();
    for (int off = 1; off < 1024; off <<= 1) {
        int add = (t >= off) ? lds[t - off] : 0;
        __syncthreads();
        lds[t] += add;
        __syncthreads();
    }
    if (t < nb) partial[t] = lds[t] - v;
    if (t == 0) rowstart[n] = total;
}

__global__ void scan_final(const int* __restrict__ deg, const int* __restrict__ partial,
                           int* __restrict__ rowstart, int* __restrict__ cursor, int n) {
    int b = blockIdx.x, t = threadIdx.x;
    int base = b * 1024 + t * 4;
    int v[4]; int s = 0;
#pragma unroll
    for (int i = 0; i < 4; ++i) { int idx = base + i; v[i] = (idx < n) ? deg[idx] : 0; s += v[i]; }
    __shared__ int lds[256];
    lds[t] = s; __syncthreads();
    for (int off = 1; off < 256; off <<= 1) {
        int add = (t >= off) ? lds[t - off] : 0;
        __syncthreads();
        lds[t] += add;
        __syncthreads();
    }
    int excl = lds[t] - s + partial[b];
#pragma unroll
    for (int i = 0; i < 4; ++i) {
        int idx = base + i;
        if (idx < n) { rowstart[idx] = excl; cursor[idx] = excl; }
        excl += v[i];
    }
}

__global__ void k_fill(const int* __restrict__ ei, int E, const int* __restrict__ flag,
                       int* __restrict__ cursor, int* __restrict__ adj) {
    int t = blockIdx.x * blockDim.x + threadIdx.x;
    if (t >= E) return;
    bool i64 = (flag[0] == 0);
    int s = edge_src(ei, E, t, i64);
    int d = edge_dst(ei, E, t, i64);
    int pos = atomicAdd(&cursor[d], 1);
    adj[pos] = s;
}

// ---- GEMM layer1: P1 = x@Wl1 ; H = x@Wr1 + b1 (lane=node, scalar weights) ----
__global__ __launch_bounds__(256) void gemm_l1(
        const float* __restrict__ x, const float* __restrict__ Wl1,
        const float* __restrict__ Wr1, const float* __restrict__ b1,
        float* __restrict__ P1, float* __restrict__ H, int n) {
    __shared__ float xl[64][129];     // padded: bank (lane+k)%32, conflict-free
    int tid = threadIdx.x;
    int base = blockIdx.x * 64;
    int nrows = n - base; if (nrows > 64) nrows = 64;
    for (int i = tid; i < nrows * 64; i += 256) {
        int nn = i >> 6, kk = i & 63;
        xl[nn][kk] = x[(size_t)(base + nn) * 64 + kk];
    }
    __syncthreads();
    int w = __builtin_amdgcn_readfirstlane(tid >> 6);  // wave id -> SGPR
    int lane = tid & 63;
    int v = base + lane;
    bool self = (w >= 2);
    const float* W = self ? Wr1 : Wl1;
    int coff = (w & 1) * 32;
    float o[32];
#pragma unroll
    for (int j = 0; j < 32; ++j) o[j] = self ? b1[coff + j] : 0.f;
#pragma unroll 2
    for (int k = 0; k < 64; ++k) {
        float ik = xl[lane][k];
        const float* wr = W + k * 64 + coff;   // wave-uniform -> s_load
#pragma unroll
        for (int j = 0; j < 32; ++j) o[j] = fmaf(ik, wr[j], o[j]);
    }
    if (v < n) {
        float* dstp = (self ? H : P1) + (size_t)v * 64 + coff;
        float4* dst = (float4*)dstp;
#pragma unroll
        for (int i = 0; i < 8; ++i)
            dst[i] = make_float4(o[4 * i], o[4 * i + 1], o[4 * i + 2], o[4 * i + 3]);
    }
}

// ---- GEMM layer2: pre2 = [ h@Wl2 | h@Wr2 + b2 ]  (row of 64 floats) ----
__global__ __launch_bounds__(256) void gemm_l2(
        const float* __restrict__ H, const float* __restrict__ Wl2,
        const float* __restrict__ Wr2, const float* __restrict__ b2,
        float* __restrict__ pre2, int n) {
    __shared__ float xl[64][65];
    int tid = threadIdx.x;
    int base = blockIdx.x * 64;
    int nrows = n - base; if (nrows > 64) nrows = 64;
    for (int i = tid; i < nrows * 64; i += 256) {
        int nn = i >> 6, kk = i & 63;
        xl[nn][kk] = H[(size_t)(base + nn) * 64 + kk];
    }
    __syncthreads();
    int w = __builtin_amdgcn_readfirstlane(tid >> 6);
    int lane = tid & 63;
    int v = base + lane;
    bool self = (w >= 2);
    const float* W = self ? Wr2 : Wl2;
    int coff = (w & 1) * 16;
    float o[16];
#pragma unroll
    for (int j = 0; j < 16; ++j) o[j] = self ? b2[coff + j] : 0.f;
#pragma unroll 4
    for (int k = 0; k < 64; ++k) {
        float ik = xl[lane][k];
        const float* wr = W + k * 32 + coff;   // wave-uniform -> s_load
#pragma unroll
        for (int j = 0; j < 16; ++j) o[j] = fmaf(ik, wr[j], o[j]);
    }
    if (v < n) {
        float4* dst = (float4*)(pre2 + (size_t)v * 64 + (self ? 32 : 0) + coff);
#pragma unroll
        for (int i = 0; i < 4; ++i)
            dst[i] = make_float4(o[4 * i], o[4 * i + 1], o[4 * i + 2], o[4 * i + 3]);
    }
}

// ---- agg1: H[v] = relu(mean_src(P1) + H[v])  (pure gather, float4 lanes) ----
__global__ __launch_bounds__(256) void agg1(
        const float* __restrict__ P1, const int* __restrict__ rowstart,
        const int* __restrict__ adj, float* __restrict__ H, int n) {
    int w = __builtin_amdgcn_readfirstlane(threadIdx.x >> 6);
    int lane = threadIdx.x & 63;
    int v = blockIdx.x * 4 + w;
    if (v >= n) return;
    int s0 = rowstart[v], s1 = rowstart[v + 1];
    int last = s1 - 1;
    int t4 = lane >> 4, f4 = lane & 15;     // 4 edges per instruction
    float4 acc = make_float4(0.f, 0.f, 0.f, 0.f);
    for (int e = s0; e < s1; e += 16) {
#pragma unroll
        for (int t = 0; t < 4; ++t) {
            int ei = e + t * 4 + t4;
            int ec = ei > last ? last : ei;
            int src = adj[ec];
            float4 vv = ((const float4*)(P1 + (size_t)src * 64))[f4];
            bool ok = ei <= last;
            acc.x += ok ? vv.x : 0.f;
            acc.y += ok ? vv.y : 0.f;
            acc.z += ok ? vv.z : 0.f;
            acc.w += ok ? vv.w : 0.f;
        }
    }
#pragma unroll
    for (int off = 16; off <= 32; off <<= 1) {
        acc.x += __shfl_xor(acc.x, off);
        acc.y += __shfl_xor(acc.y, off);
        acc.z += __shfl_xor(acc.z, off);
        acc.w += __shfl_xor(acc.w, off);
    }
    if (lane < 16) {
        float inv = 1.f / fmaxf((float)(s1 - s0), 1.f);
        float4 sv = ((const float4*)(H + (size_t)v * 64))[f4];
        float4 hv;
        hv.x = fmaxf(fmaf(acc.x, inv, sv.x), 0.f);
        hv.y = fmaxf(fmaf(acc.y, inv, sv.y), 0.f);
        hv.z = fmaxf(fmaf(acc.z, inv, sv.z), 0.f);
        hv.w = fmaxf(fmaf(acc.w, inv, sv.w), 0.f);
        ((float4*)(H + (size_t)v * 64))[f4] = hv;    // in-place: own row only
    }
}

// ---- agg2: out[v] = mean_src(z2) + S2[v]  (z2 = pre2[:, :32], S2 = [:,32:]) ----
__global__ __launch_bounds__(256) void agg2(
        const float* __restrict__ pre2, const int* __restrict__ rowstart,
        const int* __restrict__ adj, float* __restrict__ out, int n) {
    int w = __builtin_amdgcn_readfirstlane(threadIdx.x >> 6);
    int lane = threadIdx.x & 63;
    int v = blockIdx.x * 4 + w;
    if (v >= n) return;
    int s0 = rowstart[v], s1 = rowstart[v + 1];
    int last = s1 - 1;
    int t8 = lane >> 3, f4 = lane & 7;      // 8 edges per instruction
    float4 acc = make_float4(0.f, 0.f, 0.f, 0.f);
    for (int e = s0; e < s1; e += 16) {
#pragma unroll
        for (int t = 0; t < 2; ++t) {
            int ei = e + t * 8 + t8;
            int ec = ei > last ? last : ei;
            int src = adj[ec];
            float4 vv = ((const float4*)(pre2 + (size_t)src * 64))[f4];
            bool ok = ei <= last;
            acc.x += ok ? vv.x : 0.f;
            acc.y += ok ? vv.y : 0.f;
            acc.z += ok ? vv.z : 0.f;
            acc.w += ok ? vv.w : 0.f;
        }
    }
#pragma unroll
    for (int off = 8; off <= 32; off <<= 1) {
        acc.x += __shfl_xor(acc.x, off);
        acc.y += __shfl_xor(acc.y, off);
        acc.z += __shfl_xor(acc.z, off);
        acc.w += __shfl_xor(acc.w, off);
    }
    if (lane < 8) {
        float inv = 1.f / fmaxf((float)(s1 - s0), 1.f);
        float4 sv = ((const float4*)(pre2 + (size_t)v * 64 + 32))[f4];
        float4 ov;
        ov.x = fmaf(acc.x, inv, sv.x);
        ov.y = fmaf(acc.y, inv, sv.y);
        ov.z = fmaf(acc.z, inv, sv.z);
        ov.w = fmaf(acc.w, inv, sv.w);
        ((float4*)(out + (size_t)v * 32))[f4] = ov;
    }
}

extern "C" void kernel_launch(void* const* d_in, const int* in_sizes, int n_in,
                              void* d_out, int out_size, void* d_ws, size_t ws_size,
                              hipStream_t stream) {
    const float* x   = (const float*)d_in[0];
    const int*   ei  = (const int*)d_in[1];
    const float* Wl1 = (const float*)d_in[2];
    const float* Wr1 = (const float*)d_in[3];
    const float* b1  = (const float*)d_in[4];
    const float* Wl2 = (const float*)d_in[5];
    const float* Wr2 = (const float*)d_in[6];
    const float* b2  = (const float*)d_in[7];

    int N = in_sizes[0] / 64;
    int E = in_sizes[1] / 2;

    char* ws = (char*)d_ws;
    size_t o = 0;
    auto alloc = [&](size_t bytes) -> char* {
        char* p = ws + o;
        o = (o + bytes + 255) & ~(size_t)255;
        return p;
    };
    int* deg      = (int*)alloc((size_t)N * 4 + 4);   // deg[N] + flag
    int* flag     = deg + N;
    int* rowstart = (int*)alloc((size_t)(N + 1) * 4);
    int* cursor   = (int*)alloc((size_t)N * 4);
    int* partial  = (int*)alloc(4096);
    int* adj      = (int*)alloc((size_t)E * 4);
    float* P1     = (float*)alloc((size_t)N * 64 * 4); // later reused as pre2
    float* H      = (float*)alloc((size_t)N * 64 * 4); // S1 then h (in-place)
    float* pre2   = P1;                                 // P1 dead after agg1

    hipMemsetAsync(deg, 0, (size_t)N * 4 + 4, stream);

    detect_i64<<<1, 256, 0, stream>>>(ei, flag);

    int eb = (E + 255) / 256;
    k_deg<<<eb, 256, 0, stream>>>(ei, E, flag, deg);

    int NB = (N + 1023) / 1024;
    scan_partials<<<NB, 256, 0, stream>>>(deg, partial, N);
    scan_root<<<1, 1024, 0, stream>>>(partial, rowstart, N, E, NB);
    scan_final<<<NB, 256, 0, stream>>>(deg, partial, rowstart, cursor, N);

    k_fill<<<eb, 256, 0, stream>>>(ei, E, flag, cursor, adj);

    int nb64 = (N + 63) / 64;
    int nb4  = (N + 3) / 4;
    gemm_l1<<<nb64, 256, 0, stream>>>(x, Wl1, Wr1, b1, P1, H, N);
    agg1<<<nb4, 256, 0, stream>>>(P1, rowstart, adj, H, N);
    gemm_l2<<<nb64, 256, 0, stream>>>(H, Wl2, Wr2, b2, pre2, N);
    agg2<<<nb4, 256, 0, stream>>>(pre2, rowstart, adj, (float*)d_out, N);
}

// Round 4
// 221.403 us; speedup vs baseline: 3.6111x; 1.3952x over previous
//
#include <hip/hip_runtime.h>
#include <hip/hip_bf16.h>

// GraphSAGE 2-layer f32. Transform-then-aggregate (mean is linear):
//   P1 = x@Wl1, S1 = x@Wr1+b1 (dense GEMV, scalar-path weights)
//   h = relu(mean_agg(P1) + S1)        (pure gather)
//   pre2 = [h@Wl2 | h@Wr2+b2]
//   out = mean_agg(pre2[:, :32]) + pre2[:, 32:]
// CSR built per call via BUCKETED counting sort (bucket = 256 dst nodes):
// contiguous per-bucket writes kill the 17x scattered-write amplification
// of the naive atomic fill, and bucket bases double as global CSR offsets.

#define CHUNK 16384      // edges per scatter/hist workgroup
#define BCAP  6144       // bucket edge capacity (avg 3072, Poisson-safe)

// ---- edge dtype detection: int64 buffers have all-zero odd int32 words ----
__global__ void detect_i64(const int* __restrict__ ei, int* __restrict__ flag) {
    int v = ei[2 * threadIdx.x + 1];
    if (v != 0) atomicOr(flag, 1);   // 1 -> int32 layout, 0 -> int64
}

__device__ __forceinline__ int edge_src(const int* ei, int E, int e, bool i64) {
    return i64 ? ei[2 * e] : ei[e];
}
__device__ __forceinline__ int edge_dst(const int* ei, int E, int e, bool i64) {
    return i64 ? ei[2 * E + 2 * e] : ei[E + e];
}

// ---- pass 1: per-wg LDS histogram of dst>>8 -> global bucket counts ----
__global__ __launch_bounds__(256) void k_bhist(
        const int* __restrict__ ei, int E, const int* __restrict__ flag,
        int* __restrict__ gbcount, int nbuck) {
    __shared__ int lhist[512];
    int t = threadIdx.x;
    lhist[t] = 0; lhist[t + 256] = 0;
    __syncthreads();
    bool i64 = (flag[0] == 0);
    int base = blockIdx.x * CHUNK;
#pragma unroll 4
    for (int i = 0; i < CHUNK / 256; ++i) {
        int e = base + i * 256 + t;
        if (e < E) atomicAdd(&lhist[edge_dst(ei, E, e, i64) >> 8], 1);
    }
    __syncthreads();
    for (int b = t; b < nbuck; b += 256)
        if (lhist[b]) atomicAdd(&gbcount[b], lhist[b]);
}

// ---- pass 2: scan bucket counts -> gbase (= global CSR region bases) ----
__global__ __launch_bounds__(512) void k_bscan(
        const int* __restrict__ gbcount, int* __restrict__ gbase,
        int* __restrict__ gcursor, int* __restrict__ rowstart,
        int E, int n, int nbuck) {
    __shared__ int lds[513];
    int t = threadIdx.x;
    int v = (t < nbuck) ? gbcount[t] : 0;
    lds[t + 1] = v;
    if (t == 0) lds[0] = 0;
    __syncthreads();
    for (int off = 1; off < 512; off <<= 1) {
        int add = (t + 1 > off) ? lds[t + 1 - off] : 0;
        __syncthreads();
        lds[t + 1] += add;
        __syncthreads();
    }
    if (t < nbuck) { gbase[t] = lds[t]; gcursor[t] = lds[t]; }
    if (t == 0) { gbase[nbuck] = E; rowstart[n] = E; }
}

// ---- pass 3: scatter edges into bucket-grouped array (contiguous runs) ----
__global__ __launch_bounds__(256) void k_bscatter(
        const int* __restrict__ ei, int E, const int* __restrict__ flag,
        int* __restrict__ gcursor, int2* __restrict__ bucketed, int nbuck) {
    __shared__ int lhist[512];
    __shared__ int wgbase[512];
    int t = threadIdx.x;
    lhist[t] = 0; lhist[t + 256] = 0;
    __syncthreads();
    bool i64 = (flag[0] == 0);
    int base = blockIdx.x * CHUNK;
#pragma unroll 4
    for (int i = 0; i < CHUNK / 256; ++i) {
        int e = base + i * 256 + t;
        if (e < E) atomicAdd(&lhist[edge_dst(ei, E, e, i64) >> 8], 1);
    }
    __syncthreads();
    for (int b = t; b < nbuck; b += 256) {
        int c = lhist[b];
        wgbase[b] = c ? atomicAdd(&gcursor[b], c) : 0;
        lhist[b] = 0;                       // reuse as local cursor
    }
    __syncthreads();
#pragma unroll 4
    for (int i = 0; i < CHUNK / 256; ++i) {
        int e = base + i * 256 + t;
        if (e < E) {
            int s = edge_src(ei, E, e, i64);
            int d = edge_dst(ei, E, e, i64);
            int b = d >> 8;
            int r = atomicAdd(&lhist[b], 1);
            bucketed[wgbase[b] + r] = make_int2(s, d);
        }
    }
}

// ---- pass 4: per-bucket finalize: local rank+scan in LDS -> rowstart, adj ----
__global__ __launch_bounds__(256) void k_bfinal(
        const int2* __restrict__ bucketed, const int* __restrict__ gbase,
        int* __restrict__ rowstart, int* __restrict__ adj, int n) {
    __shared__ int2 ledge[BCAP];
    __shared__ unsigned short lrank[BCAP];
    __shared__ int ldeg[256];
    __shared__ int lstart[257];
    int t = threadIdx.x, b = blockIdx.x;
    int start = gbase[b], end = gbase[b + 1];
    int cnt = end - start; if (cnt > BCAP) cnt = BCAP;   // unreachable guard
    for (int i = t; i < cnt; i += 256) ledge[i] = bucketed[start + i];
    ldeg[t] = 0;
    __syncthreads();
    for (int i = t; i < cnt; i += 256) {
        int dl = ledge[i].y & 255;
        lrank[i] = (unsigned short)atomicAdd(&ldeg[dl], 1);
    }
    __syncthreads();
    int v = ldeg[t];
    lstart[t + 1] = v;
    if (t == 0) lstart[0] = 0;
    __syncthreads();
    for (int off = 1; off < 256; off <<= 1) {
        int add = (t + 1 > off) ? lstart[t + 1 - off] : 0;
        __syncthreads();
        lstart[t + 1] += add;
        __syncthreads();
    }
    int node = b * 256 + t;
    if (node < n) rowstart[node] = start + lstart[t];
    for (int i = t; i < cnt; i += 256) {
        int dl = ledge[i].y & 255;
        adj[start + lstart[dl] + lrank[i]] = ledge[i].x;
    }
}

// ---- GEMM layer1: P1 = x@Wl1 ; H = x@Wr1 + b1 (lane=node, scalar weights) ----
__global__ __launch_bounds__(256) void gemm_l1(
        const float* __restrict__ x, const float* __restrict__ Wl1,
        const float* __restrict__ Wr1, const float* __restrict__ b1,
        float* __restrict__ P1, float* __restrict__ H, int n) {
    __shared__ float xl[64][129];
    int tid = threadIdx.x;
    int base = blockIdx.x * 64;
    int nrows = n - base; if (nrows > 64) nrows = 64;
    for (int i = tid; i < nrows * 64; i += 256) {
        int nn = i >> 6, kk = i & 63;
        xl[nn][kk] = x[(size_t)(base + nn) * 64 + kk];
    }
    __syncthreads();
    int w = __builtin_amdgcn_readfirstlane(tid >> 6);
    int lane = tid & 63;
    int v = base + lane;
    bool self = (w >= 2);
    const float* W = self ? Wr1 : Wl1;
    int coff = (w & 1) * 32;
    float o[32];
#pragma unroll
    for (int j = 0; j < 32; ++j) o[j] = self ? b1[coff + j] : 0.f;
#pragma unroll 2
    for (int k = 0; k < 64; ++k) {
        float ik = xl[lane][k];
        const float* wr = W + k * 64 + coff;   // wave-uniform -> s_load
#pragma unroll
        for (int j = 0; j < 32; ++j) o[j] = fmaf(ik, wr[j], o[j]);
    }
    if (v < n) {
        float* dstp = (self ? H : P1) + (size_t)v * 64 + coff;
        float4* dst = (float4*)dstp;
#pragma unroll
        for (int i = 0; i < 8; ++i)
            dst[i] = make_float4(o[4 * i], o[4 * i + 1], o[4 * i + 2], o[4 * i + 3]);
    }
}

// ---- GEMM layer2: pre2 = [ h@Wl2 | h@Wr2 + b2 ] ----
__global__ __launch_bounds__(256) void gemm_l2(
        const float* __restrict__ H, const float* __restrict__ Wl2,
        const float* __restrict__ Wr2, const float* __restrict__ b2,
        float* __restrict__ pre2, int n) {
    __shared__ float xl[64][65];
    int tid = threadIdx.x;
    int base = blockIdx.x * 64;
    int nrows = n - base; if (nrows > 64) nrows = 64;
    for (int i = tid; i < nrows * 64; i += 256) {
        int nn = i >> 6, kk = i & 63;
        xl[nn][kk] = H[(size_t)(base + nn) * 64 + kk];
    }
    __syncthreads();
    int w = __builtin_amdgcn_readfirstlane(tid >> 6);
    int lane = tid & 63;
    int v = base + lane;
    bool self = (w >= 2);
    const float* W = self ? Wr2 : Wl2;
    int coff = (w & 1) * 16;
    float o[16];
#pragma unroll
    for (int j = 0; j < 16; ++j) o[j] = self ? b2[coff + j] : 0.f;
#pragma unroll 4
    for (int k = 0; k < 64; ++k) {
        float ik = xl[lane][k];
        const float* wr = W + k * 32 + coff;
#pragma unroll
        for (int j = 0; j < 16; ++j) o[j] = fmaf(ik, wr[j], o[j]);
    }
    if (v < n) {
        float4* dst = (float4*)(pre2 + (size_t)v * 64 + (self ? 32 : 0) + coff);
#pragma unroll
        for (int i = 0; i < 4; ++i)
            dst[i] = make_float4(o[4 * i], o[4 * i + 1], o[4 * i + 2], o[4 * i + 3]);
    }
}

// ---- agg1: H[v] = relu(mean_src(P1) + H[v])  (pure gather, float4 lanes) ----
__global__ __launch_bounds__(256) void agg1(
        const float* __restrict__ P1, const int* __restrict__ rowstart,
        const int* __restrict__ adj, float* __restrict__ H, int n) {
    int w = __builtin_amdgcn_readfirstlane(threadIdx.x >> 6);
    int lane = threadIdx.x & 63;
    int v = blockIdx.x * 4 + w;
    if (v >= n) return;
    int s0 = rowstart[v], s1 = rowstart[v + 1];
    int last = s1 - 1;
    int t4 = lane >> 4, f4 = lane & 15;     // 4 edges per instruction
    float4 acc = make_float4(0.f, 0.f, 0.f, 0.f);
    for (int e = s0; e < s1; e += 16) {
#pragma unroll
        for (int t = 0; t < 4; ++t) {
            int ei = e + t * 4 + t4;
            int ec = ei > last ? last : ei;
            int src = adj[ec];
            float4 vv = ((const float4*)(P1 + (size_t)src * 64))[f4];
            bool ok = ei <= last;
            acc.x += ok ? vv.x : 0.f;
            acc.y += ok ? vv.y : 0.f;
            acc.z += ok ? vv.z : 0.f;
            acc.w += ok ? vv.w : 0.f;
        }
    }
#pragma unroll
    for (int off = 16; off <= 32; off <<= 1) {
        acc.x += __shfl_xor(acc.x, off);
        acc.y += __shfl_xor(acc.y, off);
        acc.z += __shfl_xor(acc.z, off);
        acc.w += __shfl_xor(acc.w, off);
    }
    if (lane < 16) {
        float inv = 1.f / fmaxf((float)(s1 - s0), 1.f);
        float4 sv = ((const float4*)(H + (size_t)v * 64))[f4];
        float4 hv;
        hv.x = fmaxf(fmaf(acc.x, inv, sv.x), 0.f);
        hv.y = fmaxf(fmaf(acc.y, inv, sv.y), 0.f);
        hv.z = fmaxf(fmaf(acc.z, inv, sv.z), 0.f);
        hv.w = fmaxf(fmaf(acc.w, inv, sv.w), 0.f);
        ((float4*)(H + (size_t)v * 64))[f4] = hv;
    }
}

// ---- agg2: out[v] = mean_src(z2) + S2[v]  (z2 = pre2[:, :32], S2 = [:,32:]) ----
__global__ __launch_bounds__(256) void agg2(
        const float* __restrict__ pre2, const int* __restrict__ rowstart,
        const int* __restrict__ adj, float* __restrict__ out, int n) {
    int w = __builtin_amdgcn_readfirstlane(threadIdx.x >> 6);
    int lane = threadIdx.x & 63;
    int v = blockIdx.x * 4 + w;
    if (v >= n) return;
    int s0 = rowstart[v], s1 = rowstart[v + 1];
    int last = s1 - 1;
    int t8 = lane >> 3, f4 = lane & 7;      // 8 edges per instruction
    float4 acc = make_float4(0.f, 0.f, 0.f, 0.f);
    for (int e = s0; e < s1; e += 16) {
#pragma unroll
        for (int t = 0; t < 2; ++t) {
            int ei = e + t * 8 + t8;
            int ec = ei > last ? last : ei;
            int src = adj[ec];
            float4 vv = ((const float4*)(pre2 + (size_t)src * 64))[f4];
            bool ok = ei <= last;
            acc.x += ok ? vv.x : 0.f;
            acc.y += ok ? vv.y : 0.f;
            acc.z += ok ? vv.z : 0.f;
            acc.w += ok ? vv.w : 0.f;
        }
    }
#pragma unroll
    for (int off = 8; off <= 32; off <<= 1) {
        acc.x += __shfl_xor(acc.x, off);
        acc.y += __shfl_xor(acc.y, off);
        acc.z += __shfl_xor(acc.z, off);
        acc.w += __shfl_xor(acc.w, off);
    }
    if (lane < 8) {
        float inv = 1.f / fmaxf((float)(s1 - s0), 1.f);
        float4 sv = ((const float4*)(pre2 + (size_t)v * 64 + 32))[f4];
        float4 ov;
        ov.x = fmaf(acc.x, inv, sv.x);
        ov.y = fmaf(acc.y, inv, sv.y);
        ov.z = fmaf(acc.z, inv, sv.z);
        ov.w = fmaf(acc.w, inv, sv.w);
        ((float4*)(out + (size_t)v * 32))[f4] = ov;
    }
}

extern "C" void kernel_launch(void* const* d_in, const int* in_sizes, int n_in,
                              void* d_out, int out_size, void* d_ws, size_t ws_size,
                              hipStream_t stream) {
    const float* x   = (const float*)d_in[0];
    const int*   ei  = (const int*)d_in[1];
    const float* Wl1 = (const float*)d_in[2];
    const float* Wr1 = (const float*)d_in[3];
    const float* b1  = (const float*)d_in[4];
    const float* Wl2 = (const float*)d_in[5];
    const float* Wr2 = (const float*)d_in[6];
    const float* b2  = (const float*)d_in[7];

    int N = in_sizes[0] / 64;
    int E = in_sizes[1] / 2;
    int nbuck = (N + 255) >> 8;            // <= 512 for N <= 131072

    char* ws = (char*)d_ws;
    size_t o = 0;
    auto alloc = [&](size_t bytes) -> char* {
        char* p = ws + o;
        o = (o + bytes + 255) & ~(size_t)255;
        return p;
    };
    int* meta     = (int*)alloc((size_t)(nbuck + 1) * 4);  // flag + gbcount[nbuck]
    int* flag     = meta;
    int* gbcount  = meta + 1;
    int* gbase    = (int*)alloc((size_t)(nbuck + 1) * 4);
    int* gcursor  = (int*)alloc((size_t)nbuck * 4);
    int* rowstart = (int*)alloc((size_t)(N + 1) * 4);
    int* adj      = (int*)alloc((size_t)E * 4);
    int2* bucketed= (int2*)alloc((size_t)E * 8);
    float* P1     = (float*)alloc((size_t)N * 64 * 4);     // later reused as pre2
    float* H      = (float*)alloc((size_t)N * 64 * 4);     // S1 then h (in-place)
    float* pre2   = P1;                                    // P1 dead after agg1

    hipMemsetAsync(meta, 0, (size_t)(nbuck + 1) * 4, stream);

    detect_i64<<<1, 256, 0, stream>>>(ei, flag);

    int nwg = (E + CHUNK - 1) / CHUNK;
    k_bhist<<<nwg, 256, 0, stream>>>(ei, E, flag, gbcount, nbuck);
    k_bscan<<<1, 512, 0, stream>>>(gbcount, gbase, gcursor, rowstart, E, N, nbuck);
    k_bscatter<<<nwg, 256, 0, stream>>>(ei, E, flag, gcursor, bucketed, nbuck);
    k_bfinal<<<nbuck, 256, 0, stream>>>(bucketed, gbase, rowstart, adj, N);

    int nb64 = (N + 63) / 64;
    int nb4  = (N + 3) / 4;
    gemm_l1<<<nb64, 256, 0, stream>>>(x, Wl1, Wr1, b1, P1, H, N);
    agg1<<<nb4, 256, 0, stream>>>(P1, rowstart, adj, H, N);
    gemm_l2<<<nb64, 256, 0, stream>>>(H, Wl2, Wr2, b2, pre2, N);
    agg2<<<nb4, 256, 0, stream>>>(pre2, rowstart, adj, (float*)d_out, N);
}